// Round 1
// baseline (8031.888 us; speedup 1.0000x reference)
//
#include <hip/hip_runtime.h>
#include <math.h>

#define BATCH   32
#define A_TOTAL 8400
#define NCLS    80
#define NREG    68
#define NCH     148   // 80 cls (channel 80 of conv is discarded by reference) + 68 reg

// One block: 64 pixels (flat row-major h*w) x all 148 output channels of one level.
// 4 waves; wave wq owns channels {wq, wq+4, ..., wq+4*36} (37 each, 4*37=148).
// Weight addresses are wave-uniform -> scalar loads. x loads coalesced across the
// 64 pixel lanes. Fused post-processing from LDS, final outputs written directly.
template<int C, int H, int W, int STRIDE, int A_OFF, int LVL>
__global__ __launch_bounds__(256, 4) void fused_head(
    const float* __restrict__ x,      // [N][C][H][W]
    const float* __restrict__ wc,     // [81][C][3][3]
    const float* __restrict__ bc,     // [81]
    const float* __restrict__ wr,     // [68][C][3][3]
    const float* __restrict__ br,     // [68]
    const float* __restrict__ scales, // [3]
    float* __restrict__ out_cls,      // [N][8400][80]
    float* __restrict__ out_box)      // [N][8400][4]
{
    constexpr int HW = H * W;
    constexpr int TILES = (HW + 63) / 64;
    const int tile = blockIdx.x % TILES;
    const int n    = blockIdx.x / TILES;
    const int tid  = threadIdx.x;
    const int t    = tid & 63;
    const int wq   = __builtin_amdgcn_readfirstlane(tid >> 6);  // wave-uniform SGPR
    const int p    = tile * 64 + t;
    const bool valid = (p < HW);
    const int py = p / W;
    const int px = p % W;

    float acc[37];
#pragma unroll
    for (int j = 0; j < 37; ++j) acc[j] = 0.f;

    const float* xn = x + (size_t)n * C * HW;

    for (int c = 0; c < C; ++c) {
        const float* xc = xn + (size_t)c * HW;
        float xv[9];
#pragma unroll
        for (int dy = 0; dy < 3; ++dy) {
            const int yy  = py + dy - 1;
            const bool yok = valid & (yy >= 0) & (yy < H);
#pragma unroll
            for (int dx = 0; dx < 3; ++dx) {
                const int xx = px + dx - 1;
                const bool ok = yok & (xx >= 0) & (xx < W);
                xv[dy * 3 + dx] = ok ? xc[yy * W + xx] : 0.f;
            }
        }
#pragma unroll
        for (int j = 0; j < 37; ++j) {
            const int o = 4 * j + wq;          // output channel (0..147), wave-uniform
            const float* wp = (o < NCLS)
                ? (wc + ((size_t)o * C + c) * 9)
                : (wr + ((size_t)(o - NCLS) * C + c) * 9);
            float s = wp[0] * xv[0];
#pragma unroll
            for (int k = 1; k < 9; ++k) s += wp[k] * xv[k];
            acc[j] += s;
        }
    }

    __shared__ float outsm[NCH][65];
#pragma unroll
    for (int j = 0; j < 37; ++j) {
        const int o = 4 * j + wq;
        const float b = (o < NCLS) ? bc[o] : br[o - NCLS];
        outsm[o][t] = acc[j] + b;
    }
    __syncthreads();

    // Post-process: thread = (pixel t, quarter q). q handles cls channels
    // [q*20, q*20+20) and reg coordinate f=q.
    if (valid) {
        const int q = wq;
        const int a = A_OFF + p;
        float* oc = out_cls + ((size_t)n * A_TOTAL + a) * NCLS + q * 20;
#pragma unroll
        for (int k = 0; k < 20; k += 4) {
            float4 v;
            v.x = 1.f / (1.f + expf(-outsm[q * 20 + k + 0][t]));
            v.y = 1.f / (1.f + expf(-outsm[q * 20 + k + 1][t]));
            v.z = 1.f / (1.f + expf(-outsm[q * 20 + k + 2][t]));
            v.w = 1.f / (1.f + expf(-outsm[q * 20 + k + 3][t]));
            *(float4*)(oc + k) = v;
        }
        // softmax-integral over 17 bins for coordinate f=q
        const float sc = scales[LVL];
        float l[17];
        float m = -1e30f;
#pragma unroll
        for (int r = 0; r < 17; ++r) {
            l[r] = outsm[NCLS + q * 17 + r][t] * sc;
            m = fmaxf(m, l[r]);
        }
        float ssum = 0.f, esum = 0.f;
#pragma unroll
        for (int r = 0; r < 17; ++r) {
            const float e = expf(l[r] - m);
            ssum += e;
            esum += e * (float)r;
        }
        const float dist = esum / ssum * (float)STRIDE;
        const float base = (q & 1) ? (float)(py * STRIDE) : (float)(px * STRIDE);
        const float val  = (q < 2) ? (base - dist) : (base + dist);
        out_box[((size_t)n * A_TOTAL + a) * 4 + q] = val;
    }
}

extern "C" void kernel_launch(void* const* d_in, const int* in_sizes, int n_in,
                              void* d_out, int out_size, void* d_ws, size_t ws_size,
                              hipStream_t stream) {
    const float* x0  = (const float*)d_in[0];
    const float* x1  = (const float*)d_in[1];
    const float* x2  = (const float*)d_in[2];
    const float* wc0 = (const float*)d_in[3];
    const float* bc0 = (const float*)d_in[4];
    const float* wr0 = (const float*)d_in[5];
    const float* br0 = (const float*)d_in[6];
    const float* wc1 = (const float*)d_in[7];
    const float* bc1 = (const float*)d_in[8];
    const float* wr1 = (const float*)d_in[9];
    const float* br1 = (const float*)d_in[10];
    const float* wc2 = (const float*)d_in[11];
    const float* bc2 = (const float*)d_in[12];
    const float* wr2 = (const float*)d_in[13];
    const float* br2 = (const float*)d_in[14];
    const float* scl = (const float*)d_in[15];

    float* out_cls = (float*)d_out;
    float* out_box = (float*)d_out + (size_t)BATCH * A_TOTAL * NCLS;

    fused_head<128, 80, 80,  8,    0, 0><<<dim3(BATCH * 100), 256, 0, stream>>>(
        x0, wc0, bc0, wr0, br0, scl, out_cls, out_box);
    fused_head<256, 40, 40, 16, 6400, 1><<<dim3(BATCH * 25), 256, 0, stream>>>(
        x1, wc1, bc1, wr1, br1, scl, out_cls, out_box);
    fused_head<512, 20, 20, 32, 8000, 2><<<dim3(BATCH * 7), 256, 0, stream>>>(
        x2, wc2, bc2, wr2, br2, scl, out_cls, out_box);
}

// Round 2
// 526.335 us; speedup vs baseline: 15.2600x; 15.2600x over previous
//
#include <hip/hip_runtime.h>
#include <hip/hip_bf16.h>
#include <math.h>

#define BATCH   32
#define A_TOTAL 8400
#define NCLS    80

typedef __attribute__((ext_vector_type(8))) short bf16x8;
typedef __attribute__((ext_vector_type(4))) float f32x4;

__device__ __forceinline__ short f2bf(float f) {
    union { float f; unsigned u; } v; v.f = f;
    unsigned u = v.u + 0x7fffu + ((v.u >> 16) & 1u);   // round-nearest-even
    return (short)(u >> 16);
}

// ---------------------------------------------------------------------------
// Weight prep: Afrag[tap][kc][mf(10)][lane(64)][8] bf16, M padded 148->160.
// m in [0,80): wc row m (cls, ch 80 of conv intentionally dropped);
// m in [80,148): wr row m-80; else zero pad.
// ---------------------------------------------------------------------------
template<int C>
__global__ __launch_bounds__(256) void prep_w(const float* __restrict__ wc,
                                              const float* __restrict__ wr,
                                              __hip_bfloat16* __restrict__ af) {
    const int KC = C / 32;
    const int total = 9 * KC * 10 * 64;
    int idx = blockIdx.x * 256 + threadIdx.x;
    if (idx >= total) return;
    int l   = idx & 63;
    int rem = idx >> 6;
    int mf  = rem % 10;
    int kc  = (rem / 10) % KC;
    int tap = rem / (10 * KC);
    int m     = mf * 16 + (l & 15);
    int cbase = kc * 32 + (l >> 4) * 8;
    short v[8];
#pragma unroll
    for (int j = 0; j < 8; ++j) {
        int c = cbase + j;
        float w = 0.f;
        if (m < 80)        w = wc[((size_t)m * C + c) * 9 + tap];
        else if (m < 148)  w = wr[((size_t)(m - 80) * C + c) * 9 + tap];
        v[j] = f2bf(w);
    }
    *(bf16x8*)((short*)af + (size_t)idx * 8) = *(bf16x8*)v;
}

// ---------------------------------------------------------------------------
// NCHW fp32 -> [n][h*w][C] bf16 transpose (block: one n, one y, 64 channels)
// ---------------------------------------------------------------------------
template<int C, int H, int W>
__global__ __launch_bounds__(256) void transpose_x(const float* __restrict__ x,
                                                   __hip_bfloat16* __restrict__ xT) {
    const int CC = C / 64;
    int b   = blockIdx.x;
    int cch = b % CC;
    int y   = (b / CC) % H;
    int n   = b / (CC * H);
    __shared__ float sm[64][W + 1];
    const float* src = x + (((size_t)n * C + cch * 64) * H + y) * W;
    for (int i = threadIdx.x; i < 64 * W; i += 256) {
        int c = i / W, col = i % W;
        sm[c][col] = src[(size_t)c * H * W + col];
    }
    __syncthreads();
    short* dst = (short*)xT + ((size_t)n * H + y) * (size_t)W * C + cch * 64;
    for (int u = threadIdx.x; u < W * 8; u += 256) {
        int p = u >> 3, g = u & 7;
        short v[8];
#pragma unroll
        for (int j = 0; j < 8; ++j) v[j] = f2bf(sm[g * 8 + j][p]);
        *(bf16x8*)(dst + (size_t)p * C + g * 8) = *(bf16x8*)v;
    }
}

// ---------------------------------------------------------------------------
// Implicit-GEMM conv head: block = 160 channels x 64 pixels, 4 waves (2M x 2N)
// wave: mhalf = wid&1 (80 ch), nhalf = wid>>1 (32 px); acc 5x2 f32x4.
// Fused epilogue: bias + sigmoid (cls) / softmax-integral + distance2bbox (reg)
// ---------------------------------------------------------------------------
template<int C, int H, int W, int STRIDE, int A_OFFp, int LVL>
__global__ __launch_bounds__(256, 3) void gemm_head(
    const __hip_bfloat16* __restrict__ xT,   // [n][HW][C] bf16
    const __hip_bfloat16* __restrict__ af,   // Afrag layout
    const float* __restrict__ bc, const float* __restrict__ br,
    const float* __restrict__ scales,
    float* __restrict__ out_cls, float* __restrict__ out_box) {
    constexpr int HW    = H * W;
    constexpr int KC    = C / 32;
    constexpr int TILES = (HW + 63) / 64;
    const int tile  = blockIdx.x % TILES;
    const int n     = blockIdx.x / TILES;
    const int tid   = threadIdx.x;
    const int l     = tid & 63;
    const int wid   = tid >> 6;
    const int mhalf = wid & 1;
    const int nhalf = wid >> 1;
    const int lr    = l & 15;
    const int kg    = l >> 4;

    // per-lane B addresses + OOB masks (clamped addresses stay in-bounds)
    unsigned boff[2][9];
    unsigned bmask[2];
#pragma unroll
    for (int nf = 0; nf < 2; ++nf) {
        int p  = tile * 64 + nhalf * 32 + nf * 16 + lr;
        bool pv = p < HW;
        int pc = pv ? p : HW - 1;
        int py = pc / W, px = pc % W;
        unsigned mask = 0;
#pragma unroll
        for (int tap = 0; tap < 9; ++tap) {
            int dy = tap / 3 - 1, dx = tap % 3 - 1;
            int y = py + dy, x = px + dx;
            bool ok = pv && (y >= 0) && (y < H) && (x >= 0) && (x < W);
            int ycl = y < 0 ? 0 : (y >= H ? H - 1 : y);
            int xcl = x < 0 ? 0 : (x >= W ? W - 1 : x);
            boff[nf][tap] = (unsigned)(((ycl * W + xcl) * C) * 2) + kg * 16;
            if (ok) mask |= 1u << tap;
        }
        bmask[nf] = mask;
    }
    const char* xb = (const char*)xT + (size_t)n * HW * C * 2;

    f32x4 acc[5][2];
#pragma unroll
    for (int mf = 0; mf < 5; ++mf)
#pragma unroll
        for (int nf = 0; nf < 2; ++nf) acc[mf][nf] = (f32x4)0.f;

    // A base: frag stride 1024 B, wave's m-half offset, lane-contiguous 16 B
    const char* ab = (const char*)af + (size_t)l * 16 + (size_t)mhalf * 5 * 1024;

#pragma unroll
    for (int tap = 0; tap < 9; ++tap) {
        const bool ok0 = (bmask[0] >> tap) & 1;
        const bool ok1 = (bmask[1] >> tap) & 1;
#pragma unroll 4
        for (int kc = 0; kc < KC; ++kc) {
            bf16x8 b0 = *(const bf16x8*)(xb + boff[0][tap] + kc * 64);
            bf16x8 b1 = *(const bf16x8*)(xb + boff[1][tap] + kc * 64);
            if (!ok0) b0 = (bf16x8)(short)0;
            if (!ok1) b1 = (bf16x8)(short)0;
            const char* abase = ab + ((size_t)(tap * KC + kc) * 10) * 1024;
#pragma unroll
            for (int mf = 0; mf < 5; ++mf) {
                bf16x8 a = *(const bf16x8*)(abase + mf * 1024);
                acc[mf][0] = __builtin_amdgcn_mfma_f32_16x16x32_bf16(a, b0, acc[mf][0], 0, 0, 0);
                acc[mf][1] = __builtin_amdgcn_mfma_f32_16x16x32_bf16(a, b1, acc[mf][1], 0, 0, 0);
            }
        }
    }

    __shared__ float sm[160][68];
#pragma unroll
    for (int mf = 0; mf < 5; ++mf)
#pragma unroll
        for (int nf = 0; nf < 2; ++nf)
#pragma unroll
            for (int r = 0; r < 4; ++r)
                sm[mhalf * 80 + mf * 16 + kg * 4 + r][nhalf * 32 + nf * 16 + lr] = acc[mf][nf][r];
    __syncthreads();

    const int t = tid & 63;
    const int q = tid >> 6;
    const int p = tile * 64 + t;
    if (p < HW) {
        const int py = p / W, px = p % W;
        const int a = A_OFFp + p;
        float* oc = out_cls + ((size_t)n * A_TOTAL + a) * NCLS + q * 20;
#pragma unroll
        for (int k = 0; k < 20; k += 4) {
            float4 v;
            v.x = 1.f / (1.f + expf(-(sm[q * 20 + k + 0][t] + bc[q * 20 + k + 0])));
            v.y = 1.f / (1.f + expf(-(sm[q * 20 + k + 1][t] + bc[q * 20 + k + 1])));
            v.z = 1.f / (1.f + expf(-(sm[q * 20 + k + 2][t] + bc[q * 20 + k + 2])));
            v.w = 1.f / (1.f + expf(-(sm[q * 20 + k + 3][t] + bc[q * 20 + k + 3])));
            *(float4*)(oc + k) = v;
        }
        const float sc = scales[LVL];
        float lgt[17];
        float m = -1e30f;
#pragma unroll
        for (int r = 0; r < 17; ++r) {
            lgt[r] = (sm[80 + q * 17 + r][t] + br[q * 17 + r]) * sc;
            m = fmaxf(m, lgt[r]);
        }
        float ssum = 0.f, esum = 0.f;
#pragma unroll
        for (int r = 0; r < 17; ++r) {
            float e = expf(lgt[r] - m);
            ssum += e;
            esum += e * (float)r;
        }
        const float dist = esum / ssum * (float)STRIDE;
        const float base = (q & 1) ? (float)(py * STRIDE) : (float)(px * STRIDE);
        const float val  = (q < 2) ? (base - dist) : (base + dist);
        out_box[((size_t)n * A_TOTAL + a) * 4 + q] = val;
    }
}

extern "C" void kernel_launch(void* const* d_in, const int* in_sizes, int n_in,
                              void* d_out, int out_size, void* d_ws, size_t ws_size,
                              hipStream_t stream) {
    const float* x0  = (const float*)d_in[0];
    const float* x1  = (const float*)d_in[1];
    const float* x2  = (const float*)d_in[2];
    const float* wc0 = (const float*)d_in[3];
    const float* bc0 = (const float*)d_in[4];
    const float* wr0 = (const float*)d_in[5];
    const float* br0 = (const float*)d_in[6];
    const float* wc1 = (const float*)d_in[7];
    const float* bc1 = (const float*)d_in[8];
    const float* wr1 = (const float*)d_in[9];
    const float* br1 = (const float*)d_in[10];
    const float* wc2 = (const float*)d_in[11];
    const float* bc2 = (const float*)d_in[12];
    const float* wr2 = (const float*)d_in[13];
    const float* br2 = (const float*)d_in[14];
    const float* scl = (const float*)d_in[15];

    float* out_cls = (float*)d_out;
    float* out_box = (float*)d_out + (size_t)BATCH * A_TOTAL * NCLS;

    // ws layout (elements of bf16): A0 @0 (184320), A1 @184320 (368640),
    // A2 @552960 (737280), xT @1290240 (reused per level, max 26.2M elems)
    __hip_bfloat16* af  = (__hip_bfloat16*)d_ws;
    __hip_bfloat16* af0 = af;
    __hip_bfloat16* af1 = af + 184320;
    __hip_bfloat16* af2 = af + 552960;
    __hip_bfloat16* xT  = af + 1290240;

    prep_w<128><<<dim3(90),  256, 0, stream>>>(wc0, wr0, af0);
    prep_w<256><<<dim3(180), 256, 0, stream>>>(wc1, wr1, af1);
    prep_w<512><<<dim3(360), 256, 0, stream>>>(wc2, wr2, af2);

    transpose_x<128, 80, 80><<<dim3(32 * 80 * 2), 256, 0, stream>>>(x0, xT);
    gemm_head<128, 80, 80, 8, 0, 0><<<dim3(BATCH * 100), 256, 0, stream>>>(
        xT, af0, bc0, br0, scl, out_cls, out_box);

    transpose_x<256, 40, 40><<<dim3(32 * 40 * 4), 256, 0, stream>>>(x1, xT);
    gemm_head<256, 40, 40, 16, 6400, 1><<<dim3(BATCH * 25), 256, 0, stream>>>(
        xT, af1, bc1, br1, scl, out_cls, out_box);

    transpose_x<512, 20, 20><<<dim3(32 * 20 * 8), 256, 0, stream>>>(x2, xT);
    gemm_head<512, 20, 20, 32, 8000, 2><<<dim3(BATCH * 7), 256, 0, stream>>>(
        xT, af2, bc2, br2, scl, out_cls, out_box);
}

// Round 3
// 419.563 us; speedup vs baseline: 19.1435x; 1.2545x over previous
//
#include <hip/hip_runtime.h>
#include <hip/hip_bf16.h>
#include <math.h>

#define BATCH   32
#define A_TOTAL 8400
#define NCLS    80

typedef __attribute__((ext_vector_type(8))) short bf16x8;
typedef __attribute__((ext_vector_type(4))) float f32x4;

__device__ __forceinline__ short f2bf(float f) {
    union { float f; unsigned u; } v; v.f = f;
    unsigned u = v.u + 0x7fffu + ((v.u >> 16) & 1u);   // round-nearest-even
    return (short)(u >> 16);
}

// async global->LDS, 16B per lane; lds dest = wave-uniform base + lane*16
__device__ __forceinline__ void stage16(const void* g, void* ldsp) {
    __builtin_amdgcn_global_load_lds(
        (const __attribute__((address_space(1))) unsigned int*)g,
        (__attribute__((address_space(3))) unsigned int*)ldsp, 16, 0, 0);
}

// ---------------------------------------------------------------------------
// Weight prep: Afrag[tap][kc][mf(10)][lane(64)][8] bf16, M padded 148->160.
// granule (tap, kc-pair) = contiguous 20KB.
// ---------------------------------------------------------------------------
template<int C>
__global__ __launch_bounds__(256) void prep_w(const float* __restrict__ wc,
                                              const float* __restrict__ wr,
                                              __hip_bfloat16* __restrict__ af) {
    const int KC = C / 32;
    const int total = 9 * KC * 10 * 64;
    int idx = blockIdx.x * 256 + threadIdx.x;
    if (idx >= total) return;
    int l   = idx & 63;
    int rem = idx >> 6;
    int mf  = rem % 10;
    int kc  = (rem / 10) % KC;
    int tap = rem / (10 * KC);
    int m     = mf * 16 + (l & 15);
    int cbase = kc * 32 + (l >> 4) * 8;
    short v[8];
#pragma unroll
    for (int j = 0; j < 8; ++j) {
        int c = cbase + j;
        float w = 0.f;
        if (m < 80)        w = wc[((size_t)m * C + c) * 9 + tap];
        else if (m < 148)  w = wr[((size_t)(m - 80) * C + c) * 9 + tap];
        v[j] = f2bf(w);
    }
    *(bf16x8*)((short*)af + (size_t)idx * 8) = *(bf16x8*)v;
}

// ---------------------------------------------------------------------------
// NCHW fp32 -> [n][h*w][C] bf16 transpose; float4 global reads
// ---------------------------------------------------------------------------
template<int C, int H, int W>
__global__ __launch_bounds__(256) void transpose_x(const float* __restrict__ x,
                                                   __hip_bfloat16* __restrict__ xT) {
    const int CC = C / 64;
    int b   = blockIdx.x;
    int cch = b % CC;
    int y   = (b / CC) % H;
    int n   = b / (CC * H);
    __shared__ float sm[64][W + 1];
    const float* src = x + (((size_t)n * C + cch * 64) * H + y) * W;
    for (int i = threadIdx.x; i < 64 * (W / 4); i += 256) {
        int c = i / (W / 4), f4 = i % (W / 4);
        float4 v = *(const float4*)(src + (size_t)c * H * W + f4 * 4);
        sm[c][f4 * 4 + 0] = v.x;
        sm[c][f4 * 4 + 1] = v.y;
        sm[c][f4 * 4 + 2] = v.z;
        sm[c][f4 * 4 + 3] = v.w;
    }
    __syncthreads();
    short* dst = (short*)xT + ((size_t)n * H + y) * (size_t)W * C + cch * 64;
    for (int u = threadIdx.x; u < W * 8; u += 256) {
        int p = u >> 3, g = u & 7;
        short v[8];
#pragma unroll
        for (int j = 0; j < 8; ++j) v[j] = f2bf(sm[g * 8 + j][p]);
        *(bf16x8*)(dst + (size_t)p * C + g * 8) = *(bf16x8*)v;
    }
}

// ---------------------------------------------------------------------------
// Implicit-GEMM head, A double-buffered in LDS via global_load_lds.
// Block: 160 ch x NT px (NT = 32*NF), 4 waves (2M x 2N), acc[5][NF]/wave.
// 2-phase pipeline: stage(g+1) -> compute(g) -> syncthreads, per 2-kc granule.
// ---------------------------------------------------------------------------
template<int C, int H, int W, int STRIDE, int A_OFFp, int LVL, int NF>
__global__ __launch_bounds__(256, 3) void gemm_head(
    const __hip_bfloat16* __restrict__ xT,   // [n][HW][C] bf16
    const __hip_bfloat16* __restrict__ af,   // Afrag granule stream
    const float* __restrict__ bc, const float* __restrict__ br,
    const float* __restrict__ scales,
    float* __restrict__ out_cls, float* __restrict__ out_box) {
    constexpr int HW     = H * W;
    constexpr int NT     = NF * 32;
    constexpr int TILES  = (HW + NT - 1) / NT;
    constexpr int KC     = C / 32;
    constexpr int GR     = 9 * (KC / 2);
    constexpr int ROUNDS = NT / 64;

    __shared__ __align__(16) char lds[43520];  // union: A dbuf 40960 | epi 160*68*4

    const int tile  = blockIdx.x % TILES;
    const int n     = blockIdx.x / TILES;
    const int tid   = threadIdx.x;
    const int l     = tid & 63;
    const int wid   = tid >> 6;
    const int mhalf = wid & 1;
    const int nhalf = wid >> 1;
    const int lr    = l & 15;
    const int kg    = l >> 4;

    // prologue: stage granule 0 into buffer 0
    const char* asrc = (const char*)af;
#pragma unroll
    for (int i = 0; i < 5; ++i)
        stage16(asrc + wid * 5120 + i * 1024 + l * 16,
                &lds[wid * 5120 + i * 1024]);
    asrc += 20480;

    // pixel coords per n-frag
    int pyv[NF], pxv[NF];
    bool pval[NF];
#pragma unroll
    for (int nf = 0; nf < NF; ++nf) {
        int p = tile * NT + (nhalf * NF + nf) * 16 + lr;
        pval[nf] = p < HW;
        int pc = pval[nf] ? p : HW - 1;
        pyv[nf] = pc / W;
        pxv[nf] = pc % W;
    }
    const char* xb = (const char*)xT + (size_t)n * HW * C * 2 + kg * 16;

    f32x4 acc[5][NF];
#pragma unroll
    for (int mf = 0; mf < 5; ++mf)
#pragma unroll
        for (int nf = 0; nf < NF; ++nf) acc[mf][nf] = (f32x4)0.f;

    __syncthreads();

    unsigned buf = 0;
    int g = 0;
#pragma unroll 1
    for (int tap = 0; tap < 9; ++tap) {
        const int dy = tap / 3 - 1, dx = tap % 3 - 1;
        unsigned boff[NF];
        bool okm[NF];
#pragma unroll
        for (int nf = 0; nf < NF; ++nf) {
            int y = pyv[nf] + dy, x = pxv[nf] + dx;
            okm[nf] = pval[nf] & (y >= 0) & (y < H) & (x >= 0) & (x < W);
            int ycl = y < 0 ? 0 : (y >= H ? H - 1 : y);
            int xcl = x < 0 ? 0 : (x >= W ? W - 1 : x);
            boff[nf] = (unsigned)((ycl * W + xcl) * C * 2);
        }
#pragma unroll
        for (int g2 = 0; g2 < KC / 2; ++g2) {
            // issue next-granule A stage first (latency hides under compute)
            if (g + 1 < GR) {
#pragma unroll
                for (int i = 0; i < 5; ++i)
                    stage16(asrc + wid * 5120 + i * 1024 + l * 16,
                            &lds[(buf ^ 20480) + wid * 5120 + i * 1024]);
                asrc += 20480;
            }
            // B loads (direct global, zero-masked at borders)
            bf16x8 bv[2][NF];
#pragma unroll
            for (int kc2 = 0; kc2 < 2; ++kc2)
#pragma unroll
                for (int nf = 0; nf < NF; ++nf) {
                    bf16x8 v = *(const bf16x8*)(xb + boff[nf] + (g2 * 2 + kc2) * 64);
                    bv[kc2][nf] = okm[nf] ? v : (bf16x8)(short)0;
                }
            // MFMA from LDS A
#pragma unroll
            for (int kc2 = 0; kc2 < 2; ++kc2)
#pragma unroll
                for (int mf = 0; mf < 5; ++mf) {
                    const bf16x8 a = *(const bf16x8*)(
                        &lds[buf + ((kc2 * 10 + mhalf * 5 + mf) * 64 + l) * 16]);
#pragma unroll
                    for (int nf = 0; nf < NF; ++nf)
                        acc[mf][nf] = __builtin_amdgcn_mfma_f32_16x16x32_bf16(
                            a, bv[kc2][nf], acc[mf][nf], 0, 0, 0);
                }
            __syncthreads();
            buf ^= 20480;
            ++g;
        }
    }

    // fused epilogue, 64-px rounds through LDS [160][68]
    const float sc = scales[LVL];
    float* smf = (float*)lds;
#pragma unroll
    for (int rd = 0; rd < ROUNDS; ++rd) {
#pragma unroll
        for (int mf = 0; mf < 5; ++mf)
#pragma unroll
            for (int nf = 0; nf < NF; ++nf) {
                int colbase = (nhalf * NF + nf) * 16 - rd * 64;
                if (colbase >= 0 && colbase < 64) {
#pragma unroll
                    for (int r = 0; r < 4; ++r)
                        smf[(mhalf * 80 + mf * 16 + kg * 4 + r) * 68 + colbase + lr] =
                            acc[mf][nf][r];
                }
            }
        __syncthreads();
        const int t = tid & 63;
        const int q = wid;
        const int p = tile * NT + rd * 64 + t;
        if (p < HW) {
            const int py = p / W, px = p % W;
            const int a = A_OFFp + p;
            float* oc = out_cls + ((size_t)n * A_TOTAL + a) * NCLS + q * 20;
#pragma unroll
            for (int k = 0; k < 20; k += 4) {
                float4 v;
                v.x = 1.f / (1.f + expf(-(smf[(q * 20 + k + 0) * 68 + t] + bc[q * 20 + k + 0])));
                v.y = 1.f / (1.f + expf(-(smf[(q * 20 + k + 1) * 68 + t] + bc[q * 20 + k + 1])));
                v.z = 1.f / (1.f + expf(-(smf[(q * 20 + k + 2) * 68 + t] + bc[q * 20 + k + 2])));
                v.w = 1.f / (1.f + expf(-(smf[(q * 20 + k + 3) * 68 + t] + bc[q * 20 + k + 3])));
                *(float4*)(oc + k) = v;
            }
            float lgt[17];
            float m = -1e30f;
#pragma unroll
            for (int r = 0; r < 17; ++r) {
                lgt[r] = (smf[(80 + q * 17 + r) * 68 + t] + br[q * 17 + r]) * sc;
                m = fmaxf(m, lgt[r]);
            }
            float ssum = 0.f, esum = 0.f;
#pragma unroll
            for (int r = 0; r < 17; ++r) {
                float e = expf(lgt[r] - m);
                ssum += e;
                esum += e * (float)r;
            }
            const float dist = esum / ssum * (float)STRIDE;
            const float base = (q & 1) ? (float)(py * STRIDE) : (float)(px * STRIDE);
            const float val  = (q < 2) ? (base - dist) : (base + dist);
            out_box[((size_t)n * A_TOTAL + a) * 4 + q] = val;
        }
        __syncthreads();
    }
}

extern "C" void kernel_launch(void* const* d_in, const int* in_sizes, int n_in,
                              void* d_out, int out_size, void* d_ws, size_t ws_size,
                              hipStream_t stream) {
    const float* x0  = (const float*)d_in[0];
    const float* x1  = (const float*)d_in[1];
    const float* x2  = (const float*)d_in[2];
    const float* wc0 = (const float*)d_in[3];
    const float* bc0 = (const float*)d_in[4];
    const float* wr0 = (const float*)d_in[5];
    const float* br0 = (const float*)d_in[6];
    const float* wc1 = (const float*)d_in[7];
    const float* bc1 = (const float*)d_in[8];
    const float* wr1 = (const float*)d_in[9];
    const float* br1 = (const float*)d_in[10];
    const float* wc2 = (const float*)d_in[11];
    const float* bc2 = (const float*)d_in[12];
    const float* wr2 = (const float*)d_in[13];
    const float* br2 = (const float*)d_in[14];
    const float* scl = (const float*)d_in[15];

    float* out_cls = (float*)d_out;
    float* out_box = (float*)d_out + (size_t)BATCH * A_TOTAL * NCLS;

    __hip_bfloat16* af  = (__hip_bfloat16*)d_ws;
    __hip_bfloat16* af0 = af;
    __hip_bfloat16* af1 = af + 184320;
    __hip_bfloat16* af2 = af + 552960;
    __hip_bfloat16* xT  = af + 1290240;

    prep_w<128><<<dim3(90),  256, 0, stream>>>(wc0, wr0, af0);
    prep_w<256><<<dim3(180), 256, 0, stream>>>(wc1, wr1, af1);
    prep_w<512><<<dim3(360), 256, 0, stream>>>(wc2, wr2, af2);

    transpose_x<128, 80, 80><<<dim3(32 * 80 * 2), 256, 0, stream>>>(x0, xT);
    gemm_head<128, 80, 80, 8, 0, 0, 4><<<dim3(BATCH * 50), 256, 0, stream>>>(
        xT, af0, bc0, br0, scl, out_cls, out_box);

    transpose_x<256, 40, 40><<<dim3(32 * 40 * 4), 256, 0, stream>>>(x1, xT);
    gemm_head<256, 40, 40, 16, 6400, 1, 4><<<dim3(BATCH * 13), 256, 0, stream>>>(
        xT, af1, bc1, br1, scl, out_cls, out_box);

    transpose_x<512, 20, 20><<<dim3(32 * 20 * 8), 256, 0, stream>>>(x2, xT);
    gemm_head<512, 20, 20, 32, 8000, 2, 2><<<dim3(BATCH * 7), 256, 0, stream>>>(
        xT, af2, bc2, br2, scl, out_cls, out_box);
}